// Round 2
// baseline (563.968 us; speedup 1.0000x reference)
//
#include <hip/hip_runtime.h>
#include <hip/hip_bf16.h>

// ---------------------------------------------------------------------------
// AttentionBase: out = softmax((in@Wq^T+bq)*ds @ (mem@Wk^T+bk)^T) @ (mem@Wv^T+bv) @ Wo^T + bo
// B=8, S=2048, C=1024. All matmuls bf16 MFMA gemm_bt (A[m][k] x B[n][k]).
// Workspace-lean plan (~120 MiB):
//   - projections convert f32 A on the fly (reg-stage -> ds_write)
//   - logits GEMM stores P~ = exp(logit) bf16 directly (no f32 logit buffer);
//     softmax normalization is linear: sel = (P~ @ V) * (1/rowsum(P~))
//   - attention chunked 2 batches at a time, P~ buffer reused
//   - sel aliases dead Q rows; out-proj reads it
// ---------------------------------------------------------------------------

typedef __attribute__((ext_vector_type(8))) short short8;   // 8 bf16 = 4 VGPRs
typedef __attribute__((ext_vector_type(4))) float f32x4;

static __device__ __forceinline__ unsigned short f2bf(float f) {
  union { float f; unsigned u; } x; x.f = f;
  unsigned r = x.u + 0x7FFFu + ((x.u >> 16) & 1u);   // round-to-nearest-even
  return (unsigned short)(r >> 16);
}

static __device__ __forceinline__ float bf2f(unsigned short h) {
  union { unsigned u; float f; } x; x.u = ((unsigned)h) << 16; return x.f;
}

static __device__ __forceinline__ void g2l16(const void* g, void* l) {
  __builtin_amdgcn_global_load_lds(
      (const __attribute__((address_space(1))) void*)g,
      (__attribute__((address_space(3))) void*)l, 16, 0, 0);
}

// f32 -> bf16 conversion (weights), float4/ushort4 vectorized, grid-stride
__global__ __launch_bounds__(256) void cvt_kernel(const float* __restrict__ in,
                                                  unsigned short* __restrict__ out,
                                                  long long n4) {
  long long i = (long long)blockIdx.x * 256 + threadIdx.x;
  const long long stride = (long long)gridDim.x * 256;
  for (; i < n4; i += stride) {
    float4 v = ((const float4*)in)[i];
    ushort4 o;
    o.x = f2bf(v.x); o.y = f2bf(v.y); o.z = f2bf(v.z); o.w = f2bf(v.w);
    ((ushort4*)out)[i] = o;
  }
}

// row reciprocal-sum over 2048 bf16 -> 1/sum (f32), one block per row
__global__ __launch_bounds__(256) void rowinv_kernel(const unsigned short* __restrict__ P,
                                                     float* __restrict__ Linv) {
  const long long row = blockIdx.x;
  const unsigned short* in = P + row * 2048;
  const int tid = threadIdx.x;
  const int lane = tid & 63;
  const int wid = tid >> 6;
  short8 v = ((const short8*)in)[tid];
  float s = 0.f;
#pragma unroll
  for (int j = 0; j < 8; ++j) s += bf2f((unsigned short)v[j]);
#pragma unroll
  for (int off = 32; off; off >>= 1) s += __shfl_xor(s, off);
  __shared__ float red[4];
  if (lane == 0) red[wid] = s;
  __syncthreads();
  if (tid == 0) Linv[row] = 1.f / ((red[0] + red[1]) + (red[2] + red[3]));
}

// ---------------------------------------------------------------------------
// gemm: D[m][n] = epilogue(sum_k A[m][k]*B[n][k] (+bias[n]) (*scale))
// Tile 128x128, BK=64, 256 threads (4 waves 2x2), m97 structure.
// A_F32: A is f32, converted to bf16 during staging (reg->ds_write).
// EPI: 0=bf16 (bias+scale)  1=bf16 transposed store D[n][m]
//      2=bf16 exp(acc)      3=bf16 acc*rowLinv[row]   4=f32 (bias)
// Batched via blockIdx.z with element strides sA/sB/sD (sL for rowLinv).
// ---------------------------------------------------------------------------
#define EPI_BF16 0
#define EPI_BF16_TRANS 1
#define EPI_EXP 2
#define EPI_ROWSCALE 3
#define EPI_F32 4

template <bool A_F32, int EPI, bool HAS_BIAS>
__global__ __launch_bounds__(256, 2) void gemm_kernel(
    const void* __restrict__ Av, const unsigned short* __restrict__ B,
    const float* __restrict__ bias, const float* __restrict__ rowLinv,
    void* __restrict__ Dv,
    int K, int lda, int ldb, int ldd,
    long long sA, long long sB, long long sD, int sL, float scale) {
  const int bz = blockIdx.z;
  B += (long long)bz * sB;
  const int bm = blockIdx.x * 128;
  const int bn = blockIdx.y * 128;
  const int tid = threadIdx.x;
  const int lane = tid & 63;
  const int wid = tid >> 6;
  const int wr = (wid >> 1) * 64;  // wave row offset in tile
  const int wc = (wid & 1) * 64;   // wave col offset in tile

  __shared__ __align__(16) unsigned short As[128 * 64];
  __shared__ __align__(16) unsigned short Bs[128 * 64];

  f32x4 acc[4][4];
#pragma unroll
  for (int m = 0; m < 4; ++m)
#pragma unroll
    for (int n = 0; n < 4; ++n) acc[m][n] = (f32x4){0.f, 0.f, 0.f, 0.f};

  const int r0 = tid >> 3;        // 0..31
  const int c0 = (tid & 7) * 8;   // 0,8,...,56
  const unsigned short* Bp = B + (long long)(bn + r0) * ldb + c0;
  const unsigned short* Ab =
      A_F32 ? nullptr
            : (const unsigned short*)Av + (long long)bz * sA + (long long)(bm + r0) * lda + c0;
  const float* Af =
      A_F32 ? (const float*)Av + (long long)bz * sA + (long long)(bm + r0) * lda + c0
            : nullptr;

  for (int k0 = 0; k0 < K; k0 += 64) {
#pragma unroll
    for (int i = 0; i < 4; ++i) {
      if (A_F32) {
        const float* src = Af + (long long)(i * 32) * lda + k0;
        float4 u0 = ((const float4*)src)[0];
        float4 u1 = ((const float4*)src)[1];
        short8 pk;
        pk[0] = (short)f2bf(u0.x); pk[1] = (short)f2bf(u0.y);
        pk[2] = (short)f2bf(u0.z); pk[3] = (short)f2bf(u0.w);
        pk[4] = (short)f2bf(u1.x); pk[5] = (short)f2bf(u1.y);
        pk[6] = (short)f2bf(u1.z); pk[7] = (short)f2bf(u1.w);
        *(short8*)&As[(i * 256 + tid) * 8] = pk;
      } else {
        g2l16(Ab + (long long)(i * 32) * lda + k0, &As[(i * 256 + tid) * 8]);
      }
      g2l16(Bp + (long long)(i * 32) * ldb + k0, &Bs[(i * 256 + tid) * 8]);
    }
    __syncthreads();   // drains vmcnt + lgkmcnt
#pragma unroll
    for (int kk = 0; kk < 2; ++kk) {
      const int ko = kk * 32 + (lane >> 4) * 8;
      short8 af[4], bf[4];
#pragma unroll
      for (int m = 0; m < 4; ++m)
        af[m] = *(const short8*)&As[(wr + m * 16 + (lane & 15)) * 64 + ko];
#pragma unroll
      for (int n = 0; n < 4; ++n)
        bf[n] = *(const short8*)&Bs[(wc + n * 16 + (lane & 15)) * 64 + ko];
#pragma unroll
      for (int m = 0; m < 4; ++m)
#pragma unroll
        for (int n = 0; n < 4; ++n)
          acc[m][n] = __builtin_amdgcn_mfma_f32_16x16x32_bf16(af[m], bf[n],
                                                              acc[m][n], 0, 0, 0);
    }
    __syncthreads();
  }

  // epilogue: C/D frag layout col=lane&15, row=(lane>>4)*4+j  [m89-verified]
  const int cr = (lane >> 4) * 4;
  const int cc = lane & 15;
#pragma unroll
  for (int m = 0; m < 4; ++m) {
    const int row0 = bm + wr + m * 16 + cr;
#pragma unroll
    for (int n = 0; n < 4; ++n) {
      const int col = bn + wc + n * 16 + cc;
      const float bv = HAS_BIAS ? bias[col] : 0.f;
      if (EPI == EPI_F32) {
        float* D = (float*)Dv + (long long)bz * sD;
#pragma unroll
        for (int j = 0; j < 4; ++j)
          D[(long long)(row0 + j) * ldd + col] = acc[m][n][j] + bv;
      } else if (EPI == EPI_BF16) {
        unsigned short* D = (unsigned short*)Dv + (long long)bz * sD;
#pragma unroll
        for (int j = 0; j < 4; ++j)
          D[(long long)(row0 + j) * ldd + col] = f2bf((acc[m][n][j] + bv) * scale);
      } else if (EPI == EPI_BF16_TRANS) {
        unsigned short* D = (unsigned short*)Dv + (long long)bz * sD;
        ushort4 pk;
        pk.x = f2bf((acc[m][n][0] + bv) * scale);
        pk.y = f2bf((acc[m][n][1] + bv) * scale);
        pk.z = f2bf((acc[m][n][2] + bv) * scale);
        pk.w = f2bf((acc[m][n][3] + bv) * scale);
        *(ushort4*)&D[(long long)col * ldd + row0] = pk;
      } else if (EPI == EPI_EXP) {
        unsigned short* D = (unsigned short*)Dv + (long long)bz * sD;
#pragma unroll
        for (int j = 0; j < 4; ++j)
          D[(long long)(row0 + j) * ldd + col] = f2bf(__expf(acc[m][n][j]));
      } else {  // EPI_ROWSCALE
        unsigned short* D = (unsigned short*)Dv + (long long)bz * sD;
#pragma unroll
        for (int j = 0; j < 4; ++j) {
          const float li = rowLinv[bz * sL + row0 + j];
          D[(long long)(row0 + j) * ldd + col] = f2bf(acc[m][n][j] * li);
        }
      }
    }
  }
}

extern "C" void kernel_launch(void* const* d_in, const int* in_sizes, int n_in,
                              void* d_out, int out_size, void* d_ws, size_t ws_size,
                              hipStream_t stream) {
  (void)in_sizes; (void)n_in; (void)out_size;
  const float* input  = (const float*)d_in[0];
  const float* memory = (const float*)d_in[1];
  const float* Wq = (const float*)d_in[2];
  const float* bq = (const float*)d_in[3];
  const float* Wk = (const float*)d_in[4];
  const float* bk = (const float*)d_in[5];
  const float* Wv = (const float*)d_in[6];
  const float* bv = (const float*)d_in[7];
  const float* Wo = (const float*)d_in[8];
  const float* bo = (const float*)d_in[9];
  float* out = (float*)d_out;

  const int S = 2048, C = 1024;
  const int CB = 2;                                // batches per attention chunk
  const long long BS = 16384;                      // 8 * 2048
  const long long N_IN = BS * C;                   // 16,777,216
  const long long N_W  = (long long)C * C;         // 1,048,576

  // ---- workspace layout (256B aligned regions), ~120 MiB total ----
  char* p = (char*)d_ws;
  auto alloc = [&](size_t bytes) {
    char* r = p;
    p += (bytes + 255) & ~(size_t)255;
    return r;
  };
  unsigned short* wqb  = (unsigned short*)alloc(N_W * 2);
  unsigned short* wkb  = (unsigned short*)alloc(N_W * 2);
  unsigned short* wvb  = (unsigned short*)alloc(N_W * 2);
  unsigned short* wob  = (unsigned short*)alloc(N_W * 2);
  unsigned short* Qb   = (unsigned short*)alloc(N_IN * 2);   // [16384][1024]; later sel
  unsigned short* Kb   = (unsigned short*)alloc(N_IN * 2);   // [16384][1024]
  unsigned short* Vt   = (unsigned short*)alloc(N_IN * 2);   // [1024][16384]
  unsigned short* Pt   = (unsigned short*)alloc((long long)CB * S * S * 2);  // [CB*2048][2048]
  float*          Linv = (float*)alloc((long long)CB * S * 4);
  if ((size_t)(p - (char*)d_ws) > ws_size) return;

  // ---- weight f32 -> bf16 ----
  cvt_kernel<<<1024, 256, 0, stream>>>(Wq, wqb, N_W / 4);
  cvt_kernel<<<1024, 256, 0, stream>>>(Wk, wkb, N_W / 4);
  cvt_kernel<<<1024, 256, 0, stream>>>(Wv, wvb, N_W / 4);
  cvt_kernel<<<1024, 256, 0, stream>>>(Wo, wob, N_W / 4);

  const float depth_scale = 0.03125f;  // 1024^-0.5

  // ---- projections (A = f32 input/memory, converted in staging) ----
  // Q = (in @ Wq^T + bq) * ds  -> bf16 [16384][1024]
  gemm_kernel<true, EPI_BF16, true><<<dim3(128, 8, 1), 256, 0, stream>>>(
      input, wqb, bq, nullptr, Qb, C, C, C, C, 0, 0, 0, 0, depth_scale);
  // K = mem @ Wk^T + bk -> bf16 [16384][1024]
  gemm_kernel<true, EPI_BF16, true><<<dim3(128, 8, 1), 256, 0, stream>>>(
      memory, wkb, bk, nullptr, Kb, C, C, C, C, 0, 0, 0, 0, 1.0f);
  // Vt = (mem @ Wv^T + bv)^T -> bf16 [1024][16384]
  gemm_kernel<true, EPI_BF16_TRANS, true><<<dim3(128, 8, 1), 256, 0, stream>>>(
      memory, wvb, bv, nullptr, Vt, C, C, C, (int)BS, 0, 0, 0, 0, 1.0f);

  // ---- attention, CB batches at a time ----
  for (int c = 0; c < 8 / CB; ++c) {
    const long long qoff = (long long)c * CB * S * C;
    // P~ = exp(Q[b] @ K[b]^T) -> bf16 [CB*2048][2048]
    gemm_kernel<false, EPI_EXP, false><<<dim3(16, 16, CB), 256, 0, stream>>>(
        Qb + qoff, Kb + qoff, nullptr, nullptr, Pt,
        C, C, C, S, (long long)S * C, (long long)S * C, (long long)S * S, 0, 1.0f);
    // Linv[r] = 1 / rowsum(P~)
    rowinv_kernel<<<CB * S, 256, 0, stream>>>(Pt, Linv);
    // sel[b] = (P~ @ V[b]) * Linv  -> bf16, aliasing dead Q rows
    gemm_kernel<false, EPI_ROWSCALE, false><<<dim3(16, 8, CB), 256, 0, stream>>>(
        Pt, Vt + (long long)c * CB * S, nullptr, Linv, Qb + qoff,
        S, S, (int)BS, C, (long long)S * S, (long long)S, (long long)S * C, S, 1.0f);
  }

  // ---- out = sel @ Wo^T + bo -> f32 [16384][1024] ----
  gemm_kernel<false, EPI_F32, true><<<dim3(128, 8, 1), 256, 0, stream>>>(
      Qb, wob, bo, nullptr, out, C, C, C, C, 0, 0, 0, 0, 1.0f);
}